// Round 4
// baseline (660.015 us; speedup 1.0000x reference)
//
#include <hip/hip_runtime.h>
#include <cstdint>

typedef unsigned short ushort_t;
typedef unsigned char u8_t;
typedef long long ll_t;
typedef __bf16 bf16x8 __attribute__((ext_vector_type(8)));
typedef float f32x4 __attribute__((ext_vector_type(4)));

__device__ __forceinline__ ushort_t f2b(float f) {
  union { float f; unsigned u; } v; v.f = f;
  unsigned u = v.u;
  return (ushort_t)((u + 0x7FFFu + ((u >> 16) & 1u)) >> 16);
}
__device__ __forceinline__ float b2f(ushort_t h) {
  union { unsigned u; float f; } v; v.u = ((unsigned)h) << 16;
  return v.f;
}

// f32 -> fp8 e4m3 (x scale), pairs; n2 = n/2
__global__ __launch_bounds__(256) void k_tofp8(const float* __restrict__ s,
                                               u8_t* __restrict__ d, int n2,
                                               float scale) {
  int i = blockIdx.x * 256 + threadIdx.x;
  if (i < n2) {
    float a = s[2 * i] * scale, b = s[2 * i + 1] * scale;
    int p = __builtin_amdgcn_cvt_pk_fp8_f32(a, b, 0, false);
    ((ushort_t*)d)[i] = (ushort_t)(p & 0xffff);
  }
}

// p[b,c] = mean over 32x32 spatial; one wave per (b,c)
__global__ __launch_bounds__(256) void k_pool(const float* __restrict__ x,
                                              float* __restrict__ p) {
  int wid = threadIdx.x >> 6, lane = threadIdx.x & 63;
  int bc = blockIdx.x * 4 + wid;
  const float4* xr = (const float4*)(x + (size_t)bc * 1024);
  float s = 0.f;
#pragma unroll
  for (int i = 0; i < 4; ++i) {
    float4 t = xr[i * 64 + lane];
    s += (t.x + t.y) + (t.z + t.w);
  }
#pragma unroll
  for (int off = 32; off > 0; off >>= 1) s += __shfl_down(s, off);
  if (lane == 0) p[bc] = s * (1.0f / 1024.0f);
}

// h[b][o] = relu(bn(p[b] . kp_w1[o])); grid (24,64), block 64
__global__ __launch_bounds__(64) void k_h(
    const float* __restrict__ p, const float* __restrict__ kp_w1,
    const float* __restrict__ bn_gamma, const float* __restrict__ bn_beta,
    const float* __restrict__ bn_mean, const float* __restrict__ bn_var,
    float* __restrict__ hbuf) {
  int o = blockIdx.x, b = blockIdx.y, lane = threadIdx.x;
  const float* pr = p + b * 384;
  const float* wr = kp_w1 + o * 384;
  float s = 0.f;
#pragma unroll
  for (int i = 0; i < 6; ++i) {
    int c = i * 64 + lane;
    s += pr[c] * wr[c];
  }
#pragma unroll
  for (int off = 32; off > 0; off >>= 1) s += __shfl_down(s, off);
  if (lane == 0) {
    float a = (s - bn_mean[o]) * rsqrtf(bn_var[o] + 1e-5f) * bn_gamma[o] + bn_beta[o];
    hbuf[b * 24 + o] = fmaxf(a, 0.f);
  }
}

// praw[b][j] = h[b].kp_w2[j] + kp_b2[j]; partial sums -> part; grid (96,64)
__global__ __launch_bounds__(256) void k_praw(
    const float* __restrict__ hbuf, const float* __restrict__ kp_w2,
    const float* __restrict__ kp_b2, float* __restrict__ praw,
    float2* __restrict__ part) {
  __shared__ float wrow[256 * 25];
  __shared__ float hs[24];
  __shared__ float r1[256], r2[256];
  int bx = blockIdx.x, b = blockIdx.y, tid = threadIdx.x;
  int j0 = bx * 256;
  for (int t = tid; t < 6144; t += 256) {
    int row = t / 24, col = t - row * 24;
    wrow[row * 25 + col] = kp_w2[(size_t)j0 * 24 + t];
  }
  if (tid < 24) hs[tid] = hbuf[b * 24 + tid];
  __syncthreads();
  float a = kp_b2[j0 + tid];
  const float* wr = wrow + tid * 25;
#pragma unroll
  for (int r = 0; r < 24; ++r) a += hs[r] * wr[r];
  praw[(size_t)b * 24576 + j0 + tid] = a;
  r1[tid] = a; r2[tid] = a * a;
  __syncthreads();
  for (int off = 128; off > 0; off >>= 1) {
    if (tid < off) { r1[tid] += r1[tid + off]; r2[tid] += r2[tid + off]; }
    __syncthreads();
  }
  if (tid == 0) part[b * 96 + bx] = make_float2(r1[0], r2[0]);
}

// stats[b] = (u, rsqrt(var)); grid 64, block 128
__global__ __launch_bounds__(128) void k_pstat(const float2* __restrict__ part,
                                               float2* __restrict__ stats) {
  __shared__ float r1[128], r2[128];
  int b = blockIdx.x, tid = threadIdx.x;
  float2 v = (tid < 96) ? part[b * 96 + tid] : make_float2(0.f, 0.f);
  r1[tid] = v.x; r2[tid] = v.y;
  __syncthreads();
  for (int off = 64; off > 0; off >>= 1) {
    if (tid < off) { r1[tid] += r1[tid + off]; r2[tid] += r2[tid + off]; }
    __syncthreads();
  }
  if (tid == 0) {
    float u = r1[0] * (1.f / 24576.f);
    float var = r2[0] * (1.f / 24576.f) - u * u;
    stats[b] = make_float2(u, rsqrtf(var + 1e-12f));
  }
}

// circulant conv per (b,c); writes y NCHW bf16 = conv + bias. grid (384, 64)
__global__ __launch_bounds__(256) void k_conv(const float* __restrict__ x,
                                              const float* __restrict__ praw,
                                              const float2* __restrict__ stats,
                                              const float* __restrict__ fn_std,
                                              const float* __restrict__ fn_mean,
                                              const float* __restrict__ bias,
                                              ushort_t* __restrict__ y) {
  __shared__ float xs[1024];
  __shared__ float pe[32];
  __shared__ float kn[32];
  int c = blockIdx.x, b = blockIdx.y;
  int tid = threadIdx.x;
  size_t plane = ((size_t)b * 384 + c) * 1024;
  float4 xv = ((const float4*)(x + plane))[tid];
  if (tid < 32) {
    float2 st = stats[b];
    int j1 = c * 32 + tid;
    int j2 = (384 + c) * 32 + tid;
    pe[tid] = (praw[(size_t)b * 24576 + j1] - st.x) * st.y * fn_std[j1] + fn_mean[j1];
    kn[tid] = (praw[(size_t)b * 24576 + j2] - st.x) * st.y * fn_std[j2] + fn_mean[j2];
  }
  __syncthreads();
  const bool hm = (c < 192);
  {
    int e0 = tid * 4;
    float4 t;
    if (hm) {
      float pv = pe[e0 >> 5];
      t.x = xv.x + pv; t.y = xv.y + pv; t.z = xv.z + pv; t.w = xv.w + pv;
    } else {
      int w0 = e0 & 31;
      t.x = xv.x + pe[w0]; t.y = xv.y + pe[w0 + 1];
      t.z = xv.z + pe[w0 + 2]; t.w = xv.w + pe[w0 + 3];
    }
    *(float4*)(xs + e0) = t;
  }
  __syncthreads();
  int ww = tid & 31, hh0 = (tid >> 5) * 4;
  float a0 = 0, a1 = 0, a2 = 0, a3 = 0;
  if (hm) {
    float c0 = xs[hh0 * 32 + ww], c1 = xs[(hh0 + 1) * 32 + ww];
    float c2 = xs[(hh0 + 2) * 32 + ww], c3 = xs[(hh0 + 3) * 32 + ww];
#pragma unroll
    for (int d = 0; d < 32; ++d) {
      float kv = kn[d];
      a0 += kv * c0; a1 += kv * c1; a2 += kv * c2; a3 += kv * c3;
      c0 = c1; c1 = c2; c2 = c3;
      c3 = xs[(((hh0 + d + 4) & 31) << 5) + ww];
    }
  } else {
#pragma unroll
    for (int d = 0; d < 32; ++d) {
      float kv = kn[d];
      int wc = (ww + d) & 31;
      a0 += kv * xs[(hh0    ) * 32 + wc];
      a1 += kv * xs[(hh0 + 1) * 32 + wc];
      a2 += kv * xs[(hh0 + 2) * 32 + wc];
      a3 += kv * xs[(hh0 + 3) * 32 + wc];
    }
  }
  float bv = bias[c];
  ushort_t* yo = y + plane;
  yo[(hh0    ) * 32 + ww] = f2b(a0 + bv);
  yo[(hh0 + 1) * 32 + ww] = f2b(a1 + bv);
  yo[(hh0 + 2) * 32 + ww] = f2b(a2 + bv);
  yo[(hh0 + 3) * 32 + ww] = f2b(a3 + bv);
}

// LayerNorm over C=384 + NCHW->NHWC transpose; out tn fp8. Block per (b,h).
__global__ __launch_bounds__(256) void k_lnT(const ushort_t* __restrict__ y,
                                             const float* __restrict__ lw,
                                             const float* __restrict__ lb,
                                             u8_t* __restrict__ tn) {
  __shared__ u8_t tl[32 * 432];      // [w][c] fp8, stride 432 (16-mult, 4-way ok)
  __shared__ float rsum[8][32], rsq[8][32];
  __shared__ float smu[32], srs[32];
  int bh = blockIdx.x;
  int b = bh >> 5, h = bh & 31;
  int tid = threadIdx.x;
  int w = tid & 31, cg = tid >> 5;
  const ushort_t* base = y + ((size_t)b * 384) * 1024 + h * 32 + w;
  float v[48];
  float s1 = 0.f, s2 = 0.f;
#pragma unroll
  for (int k = 0; k < 48; ++k) {
    int c = cg * 48 + k;
    float f = b2f(base[(size_t)c * 1024]);
    v[k] = f; s1 += f; s2 += f * f;
  }
  rsum[cg][w] = s1; rsq[cg][w] = s2;
  __syncthreads();
  if (tid < 32) {
    float a = 0.f, q = 0.f;
#pragma unroll
    for (int g = 0; g < 8; ++g) { a += rsum[g][tid]; q += rsq[g][tid]; }
    float mu = a * (1.f / 384.f);
    float var = q * (1.f / 384.f) - mu * mu;
    smu[tid] = mu; srs[tid] = rsqrtf(var + 1e-6f);
  }
  __syncthreads();
  float mu = smu[w], rs = srs[w];
#pragma unroll
  for (int k = 0; k < 48; k += 4) {
    int c = cg * 48 + k;
    float va = (v[k    ] - mu) * rs * lw[c    ] + lb[c    ];
    float vb = (v[k + 1] - mu) * rs * lw[c + 1] + lb[c + 1];
    float vc = (v[k + 2] - mu) * rs * lw[c + 2] + lb[c + 2];
    float vd = (v[k + 3] - mu) * rs * lw[c + 3] + lb[c + 3];
    int pk = __builtin_amdgcn_cvt_pk_fp8_f32(va, vb, 0, false);
    pk = __builtin_amdgcn_cvt_pk_fp8_f32(vc, vd, pk, true);
    *(unsigned*)(tl + w * 432 + c) = (unsigned)pk;
  }
  __syncthreads();
  u8_t* orow = tn + (size_t)bh * 12288;
#pragma unroll
  for (int i = 0; i < 3; ++i) {
    int flat16 = i * 256 + tid;          // 768 x 16B chunks
    int ww = flat16 / 24, c16 = (flat16 % 24) * 16;
    *(uint4*)(orow + ww * 384 + c16) = *(const uint4*)(tl + ww * 432 + c16);
  }
}

__device__ __forceinline__ void gl_lds16(const void* g, void* l) {
  __builtin_amdgcn_global_load_lds(
      (const __attribute__((address_space(1))) unsigned int*)g,
      (__attribute__((address_space(3))) unsigned int*)l, 16, 0, 0);
}

// GEMM1 (fp8, BK=64): hid[m,n] = fp8(gelu(sum_k tn[m,k]*w1s[n,k]/256 + b1[n]))
// grid (512 m-tiles, 12 n-tiles) -> A-tile sharers land on one XCD
__global__ __launch_bounds__(256) void k_gemm1(const u8_t* __restrict__ A,
                                               const u8_t* __restrict__ Bt,
                                               const float* __restrict__ bias,
                                               u8_t* __restrict__ out,
                                               int N, int K) {
  __shared__ __align__(16) u8_t As[128 * 64];
  __shared__ __align__(16) u8_t Bs[128 * 64];
  const int tid = threadIdx.x;
  const int wid = tid >> 6;
  const int lane = tid & 63;
  const int quad = lane >> 4;
  const int l16 = lane & 15;
  const int m0 = blockIdx.x * 128;
  const int n0 = blockIdx.y * 128;
  const int wm = (wid & 1) * 64;
  const int wn = (wid >> 1) * 64;
  const int row = tid >> 2;
  const int seg = tid & 3;
  const u8_t* Ag0 = A + (size_t)(m0 + row) * K + seg * 16;
  const u8_t* Ag1 = Ag0 + (size_t)64 * K;
  const u8_t* Bg0 = Bt + (size_t)(n0 + row) * K + seg * 16;
  const u8_t* Bg1 = Bg0 + (size_t)64 * K;
  u8_t* AsW = As + wid * 1024;
  u8_t* BsW = Bs + wid * 1024;
  f32x4 acc[4][4] = {};
  for (int k0 = 0; k0 < K; k0 += 64) {
    __syncthreads();
    gl_lds16(Ag0 + k0, AsW);
    gl_lds16(Ag1 + k0, AsW + 4096);
    gl_lds16(Bg0 + k0, BsW);
    gl_lds16(Bg1 + k0, BsW + 4096);
    __syncthreads();
    ll_t a0[4], a1[4], b0[4], b1[4];
#pragma unroll
    for (int i = 0; i < 4; ++i) {
      const u8_t* pa = As + (wm + i * 16 + l16) * 64 + quad * 8;
      a0[i] = *(const ll_t*)pa;
      a1[i] = *(const ll_t*)(pa + 32);
    }
#pragma unroll
    for (int j = 0; j < 4; ++j) {
      const u8_t* pb = Bs + (wn + j * 16 + l16) * 64 + quad * 8;
      b0[j] = *(const ll_t*)pb;
      b1[j] = *(const ll_t*)(pb + 32);
    }
#pragma unroll
    for (int i = 0; i < 4; ++i)
#pragma unroll
      for (int j = 0; j < 4; ++j) {
        acc[i][j] = __builtin_amdgcn_mfma_f32_16x16x32_fp8_fp8(a0[i], b0[j], acc[i][j], 0, 0, 0);
        acc[i][j] = __builtin_amdgcn_mfma_f32_16x16x32_fp8_fp8(a1[i], b1[j], acc[i][j], 0, 0, 0);
      }
  }
#pragma unroll
  for (int i = 0; i < 4; ++i) {
    int mB = m0 + wm + i * 16 + quad * 4;
#pragma unroll
    for (int j = 0; j < 4; ++j) {
      int n = n0 + wn + j * 16 + l16;
      float bv = bias[n];
#pragma unroll
      for (int r = 0; r < 4; ++r) {
        float v = acc[i][j][r] * (1.0f / 256.0f) + bv;
        v = v / (1.0f + __expf(-1.702f * v));   // sigmoid-gelu, err masked by gamma
        int pk = __builtin_amdgcn_cvt_pk_fp8_f32(v, v, 0, false);
        out[(size_t)(mB + r) * N + n] = (u8_t)(pk & 0xff);
      }
    }
  }
}

// GEMM2 transposed (fp8, BK=64): out'[c][m] = x + (w2s@hid^T/256 + b2[c])*gamma[c]
// A = w2s [384][1536], Bt = hid [65536][1536]; grid (512 m-tiles, 3 c-tiles)
__global__ __launch_bounds__(256) void k_gemm2(const u8_t* __restrict__ Bt,
                                               const u8_t* __restrict__ A,
                                               const float* __restrict__ bias,
                                               const float* __restrict__ scale,
                                               const float* __restrict__ x,
                                               float* __restrict__ out) {
  const int K = 1536;
  __shared__ __align__(16) u8_t As[128 * 64];
  __shared__ __align__(16) u8_t Bs[128 * 64];
  const int tid = threadIdx.x;
  const int wid = tid >> 6;
  const int lane = tid & 63;
  const int quad = lane >> 4;
  const int l16 = lane & 15;
  const int c0 = blockIdx.y * 128;     // rows of C' (channel dim)
  const int mm0 = blockIdx.x * 128;    // cols of C' (spatial*batch dim)
  const int wm = (wid & 1) * 64;
  const int wn = (wid >> 1) * 64;
  const int row = tid >> 2;
  const int seg = tid & 3;
  const u8_t* Ag0 = A + (size_t)(c0 + row) * K + seg * 16;
  const u8_t* Ag1 = Ag0 + (size_t)64 * K;
  const u8_t* Bg0 = Bt + (size_t)(mm0 + row) * K + seg * 16;
  const u8_t* Bg1 = Bg0 + (size_t)64 * K;
  u8_t* AsW = As + wid * 1024;
  u8_t* BsW = Bs + wid * 1024;
  f32x4 acc[4][4] = {};
  for (int k0 = 0; k0 < K; k0 += 64) {
    __syncthreads();
    gl_lds16(Ag0 + k0, AsW);
    gl_lds16(Ag1 + k0, AsW + 4096);
    gl_lds16(Bg0 + k0, BsW);
    gl_lds16(Bg1 + k0, BsW + 4096);
    __syncthreads();
    ll_t a0[4], a1[4], b0[4], b1[4];
#pragma unroll
    for (int i = 0; i < 4; ++i) {
      const u8_t* pa = As + (wm + i * 16 + l16) * 64 + quad * 8;
      a0[i] = *(const ll_t*)pa;
      a1[i] = *(const ll_t*)(pa + 32);
    }
#pragma unroll
    for (int j = 0; j < 4; ++j) {
      const u8_t* pb = Bs + (wn + j * 16 + l16) * 64 + quad * 8;
      b0[j] = *(const ll_t*)pb;
      b1[j] = *(const ll_t*)(pb + 32);
    }
#pragma unroll
    for (int i = 0; i < 4; ++i)
#pragma unroll
      for (int j = 0; j < 4; ++j) {
        acc[i][j] = __builtin_amdgcn_mfma_f32_16x16x32_fp8_fp8(a0[i], b0[j], acc[i][j], 0, 0, 0);
        acc[i][j] = __builtin_amdgcn_mfma_f32_16x16x32_fp8_fp8(a1[i], b1[j], acc[i][j], 0, 0, 0);
      }
  }
  // C'[c][m]: rows c = c0+wm+i*16+quad*4+r, cols m = mm0+wn+j*16+l16 (NCHW direct)
#pragma unroll
  for (int i = 0; i < 4; ++i) {
    int cB = c0 + wm + i * 16 + quad * 4;
#pragma unroll
    for (int j = 0; j < 4; ++j) {
      int m = mm0 + wn + j * 16 + l16;
      int b = m >> 10, sp = m & 1023;
#pragma unroll
      for (int r = 0; r < 4; ++r) {
        int c = cB + r;
        float v = (acc[i][j][r] * (1.0f / 256.0f) + bias[c]) * scale[c];
        size_t ga = (((size_t)b * 384 + c) << 10) + sp;
        out[ga] = x[ga] + v;
      }
    }
  }
}

extern "C" void kernel_launch(void* const* d_in, const int* in_sizes, int n_in,
                              void* d_out, int out_size, void* d_ws, size_t ws_size,
                              hipStream_t stream) {
  const float* x        = (const float*)d_in[0];
  const float* kp_w1    = (const float*)d_in[1];
  const float* bn_gamma = (const float*)d_in[2];
  const float* bn_beta  = (const float*)d_in[3];
  const float* bn_mean  = (const float*)d_in[4];
  const float* bn_var   = (const float*)d_in[5];
  const float* kp_w2    = (const float*)d_in[6];
  const float* kp_b2    = (const float*)d_in[7];
  const float* fn_std   = (const float*)d_in[8];
  const float* fn_mean  = (const float*)d_in[9];
  const float* bias     = (const float*)d_in[10];
  const float* ln_w     = (const float*)d_in[11];
  const float* ln_b     = (const float*)d_in[12];
  const float* w1       = (const float*)d_in[13];
  const float* b1       = (const float*)d_in[14];
  const float* w2       = (const float*)d_in[15];
  const float* b2       = (const float*)d_in[16];
  const float* gamma    = (const float*)d_in[17];
  float* out = (float*)d_out;

  char* ws = (char*)d_ws;
  float*    praw   = (float*)(ws + 0);            // 6291456
  float*    pB     = (float*)(ws + 6291456);      // 98304
  float*    hbuf   = (float*)(ws + 6389760);      // 6144
  float2*   part   = (float2*)(ws + 6395904);     // 49152
  float2*   stats  = (float2*)(ws + 6445056);     // 512
  u8_t*     w1f8   = (u8_t*)(ws + 6445568);       // 589824
  u8_t*     w2f8   = (u8_t*)(ws + 7035392);       // 589824
  ushort_t* ybuf   = (ushort_t*)(ws + 7625216);   // 50331648 (NCHW bf16)
  u8_t*     tn     = (u8_t*)(ws + 57956864);      // 25165824 (NHWC fp8)
  u8_t*     hid    = (u8_t*)(ws + 83122688);      // 100663296 (fp8)
  // total ~184 MB (ws >= 310 MB confirmed by R3 un-chunked path)

  k_tofp8<<<1152, 256, 0, stream>>>(w1, w1f8, 294912, 256.0f);
  k_tofp8<<<1152, 256, 0, stream>>>(w2, w2f8, 294912, 256.0f);
  k_pool<<<6144, 256, 0, stream>>>(x, pB);
  k_h<<<dim3(24, 64), 64, 0, stream>>>(pB, kp_w1, bn_gamma, bn_beta, bn_mean,
                                       bn_var, hbuf);
  k_praw<<<dim3(96, 64), 256, 0, stream>>>(hbuf, kp_w2, kp_b2, praw, part);
  k_pstat<<<64, 128, 0, stream>>>(part, stats);
  k_conv<<<dim3(384, 64), 256, 0, stream>>>(x, praw, stats, fn_std, fn_mean,
                                            bias, ybuf);
  k_lnT<<<2048, 256, 0, stream>>>(ybuf, ln_w, ln_b, tn);
  k_gemm1<<<dim3(512, 12), 256, 0, stream>>>(tn, w1f8, b1, hid, 1536, 384);
  k_gemm2<<<dim3(512, 3), 256, 0, stream>>>(hid, w2f8, b2, gamma, x, out);
}